// Round 1
// baseline (2005.255 us; speedup 1.0000x reference)
//
#include <hip/hip_runtime.h>

#define HDIM 64

// ---------------- scatter-add aggregation ----------------
// thread = (edge, quarter-row); 16 lanes per edge, float4 gather + 4 atomics
__global__ __launch_bounds__(256) void scatter_k(
    const float4* __restrict__ x4, const float* __restrict__ ew,
    const int* __restrict__ src, const int* __restrict__ dst,
    float* __restrict__ agg, int E)
{
    int idx = blockIdx.x * 256 + threadIdx.x;
    int e = idx >> 4;
    if (e >= E) return;
    int q = idx & 15;
    int s = src[e], t = dst[e];
    float w = ew[e];
    float4 xv = x4[(size_t)s * 16 + q];
    float* ap = agg + (size_t)t * 64 + q * 4;
    atomicAdd(ap + 0, xv.x * w);
    atomicAdd(ap + 1, xv.y * w);
    atomicAdd(ap + 2, xv.z * w);
    atomicAdd(ap + 3, xv.w * w);
}

// ---------------- fused GEMM (+input transform) + BN-stats ----------------
// MODE 0: in = x, h = (1+eps)*x + agg          -> z1 = h@W1 + b1, stats1
// MODE 1: in = z1, h = relu(z1*scale + shift)  -> z2 = h@W2 + b2, stats2
// block = 256 threads (4 waves), 128 rows per block.
// wave w owns cols [16w,16w+16); lane owns rows r0=2*lane, r0+1.
template <int MODE>
__global__ __launch_bounds__(256) void gemm_k(
    const float* __restrict__ in,
    const float* __restrict__ agg,
    const float* __restrict__ epsp,
    const float* __restrict__ scale,
    const float* __restrict__ shift,
    const float* __restrict__ W,
    const float* __restrict__ bias,
    float* __restrict__ out,
    float* __restrict__ S1, float* __restrict__ S2,
    int Nn)
{
    __shared__ float Wl[64 * 64];
    __shared__ float hT[64 * 130];   // [k][row], rows padded 128->130

    const int t = threadIdx.x;
    const int base = blockIdx.x * 128;

    // stage W (coalesced float4 copy)
    {
        const float4* W4 = (const float4*)W;
        float4* Wl4 = (float4*)Wl;
#pragma unroll
        for (int i = 0; i < 4; ++i) Wl4[t + i * 256] = W4[t + i * 256];
    }

    const float epsv = (MODE == 0) ? (1.0f + *epsp) : 0.0f;
    const float4* in4 = (const float4*)in;
    const float4* agg4 = (const float4*)agg;

    // stage input rows -> transposed LDS tile hT[k][row]
#pragma unroll
    for (int i = 0; i < 8; ++i) {
        int c = t + i * 256;        // 0..2047 : 128 rows x 16 float4-chunks
        int row = c >> 4;
        int kc = c & 15;
        int k0 = kc * 4;
        float4 h4 = make_float4(0.f, 0.f, 0.f, 0.f);
        int grow = base + row;
        if (grow < Nn) {
            float4 v = in4[(size_t)grow * 16 + kc];
            if (MODE == 0) {
                float4 a = agg4[(size_t)grow * 16 + kc];
                h4.x = fmaf(epsv, v.x, a.x);
                h4.y = fmaf(epsv, v.y, a.y);
                h4.z = fmaf(epsv, v.z, a.z);
                h4.w = fmaf(epsv, v.w, a.w);
            } else {
                h4.x = fmaxf(fmaf(v.x, scale[k0 + 0], shift[k0 + 0]), 0.f);
                h4.y = fmaxf(fmaf(v.y, scale[k0 + 1], shift[k0 + 1]), 0.f);
                h4.z = fmaxf(fmaf(v.z, scale[k0 + 2], shift[k0 + 2]), 0.f);
                h4.w = fmaxf(fmaf(v.w, scale[k0 + 3], shift[k0 + 3]), 0.f);
            }
        }
        hT[(k0 + 0) * 130 + row] = h4.x;
        hT[(k0 + 1) * 130 + row] = h4.y;
        hT[(k0 + 2) * 130 + row] = h4.z;
        hT[(k0 + 3) * 130 + row] = h4.w;
    }
    __syncthreads();

    const int wv = t >> 6;
    const int lane = t & 63;
    const int c0 = wv * 16;
    const int r0 = lane * 2;

    float acc0[16], acc1[16];
#pragma unroll
    for (int j = 0; j < 16; ++j) { acc0[j] = 0.f; acc1[j] = 0.f; }

#pragma unroll 8
    for (int k = 0; k < 64; ++k) {
        float2 hv = *(const float2*)&hT[k * 130 + r0];
        const float4* wp = (const float4*)&Wl[k * 64 + c0];
        float wvv[16];
        *(float4*)&wvv[0]  = wp[0];
        *(float4*)&wvv[4]  = wp[1];
        *(float4*)&wvv[8]  = wp[2];
        *(float4*)&wvv[12] = wp[3];
#pragma unroll
        for (int j = 0; j < 16; ++j) {
            acc0[j] = fmaf(hv.x, wvv[j], acc0[j]);
            acc1[j] = fmaf(hv.y, wvv[j], acc1[j]);
        }
    }

    // epilogue: bias, store z, accumulate BN stats
    const int grow0 = base + r0;
    const int grow1 = grow0 + 1;
    const bool v0 = grow0 < Nn, v1 = grow1 < Nn;

    float zr0[16], zr1[16];
#pragma unroll
    for (int j = 0; j < 16; ++j) {
        float b = bias[c0 + j];
        zr0[j] = acc0[j] + b;
        zr1[j] = acc1[j] + b;
    }
    if (v0) {
        float4* o = (float4*)&out[(size_t)grow0 * 64 + c0];
        o[0] = make_float4(zr0[0], zr0[1], zr0[2], zr0[3]);
        o[1] = make_float4(zr0[4], zr0[5], zr0[6], zr0[7]);
        o[2] = make_float4(zr0[8], zr0[9], zr0[10], zr0[11]);
        o[3] = make_float4(zr0[12], zr0[13], zr0[14], zr0[15]);
    }
    if (v1) {
        float4* o = (float4*)&out[(size_t)grow1 * 64 + c0];
        o[0] = make_float4(zr1[0], zr1[1], zr1[2], zr1[3]);
        o[1] = make_float4(zr1[4], zr1[5], zr1[6], zr1[7]);
        o[2] = make_float4(zr1[8], zr1[9], zr1[10], zr1[11]);
        o[3] = make_float4(zr1[12], zr1[13], zr1[14], zr1[15]);
    }

    float s1[16], s2[16];
#pragma unroll
    for (int j = 0; j < 16; ++j) {
        float a = v0 ? zr0[j] : 0.f;
        float b = v1 ? zr1[j] : 0.f;
        s1[j] = a + b;
        s2[j] = a * a + b * b;
    }
#pragma unroll
    for (int m = 1; m < 64; m <<= 1) {
#pragma unroll
        for (int j = 0; j < 16; ++j) {
            s1[j] += __shfl_xor(s1[j], m);
            s2[j] += __shfl_xor(s2[j], m);
        }
    }
    if (lane == 0) {
#pragma unroll
        for (int j = 0; j < 16; ++j) {
            atomicAdd(&S1[c0 + j], s1[j]);
            atomicAdd(&S2[c0 + j], s2[j]);
        }
    }
}

// ---------------- BN finalize: scale/shift from sums ----------------
__global__ __launch_bounds__(64) void finalize_k(
    const float* __restrict__ S1, const float* __restrict__ S2,
    const float* __restrict__ gamma, const float* __restrict__ beta,
    float* __restrict__ scale, float* __restrict__ shift, float invN)
{
    int c = threadIdx.x;
    float mean = S1[c] * invN;
    float var = fmaxf(S2[c] * invN - mean * mean, 0.f);
    float g = gamma[c] / sqrtf(var + 1e-5f);
    scale[c] = g;
    shift[c] = beta[c] - mean * g;
}

// ---------------- final BN+ReLU (in-place on d_out) ----------------
__global__ __launch_bounds__(256) void bnrelu_k(
    float4* __restrict__ z, const float* __restrict__ scale,
    const float* __restrict__ shift, int total4)
{
    int idx = blockIdx.x * 256 + threadIdx.x;
    if (idx >= total4) return;
    int c0 = (idx & 15) * 4;
    float4 v = z[idx];
    v.x = fmaxf(fmaf(v.x, scale[c0 + 0], shift[c0 + 0]), 0.f);
    v.y = fmaxf(fmaf(v.y, scale[c0 + 1], shift[c0 + 1]), 0.f);
    v.z = fmaxf(fmaf(v.z, scale[c0 + 2], shift[c0 + 2]), 0.f);
    v.w = fmaxf(fmaf(v.w, scale[c0 + 3], shift[c0 + 3]), 0.f);
    z[idx] = v;
}

extern "C" void kernel_launch(void* const* d_in, const int* in_sizes, int n_in,
                              void* d_out, int out_size, void* d_ws, size_t ws_size,
                              hipStream_t stream)
{
    const float* x    = (const float*)d_in[0];
    const float* ew   = (const float*)d_in[1];
    const float* epsp = (const float*)d_in[2];
    const float* W1   = (const float*)d_in[3];
    const float* b1   = (const float*)d_in[4];
    const float* g1   = (const float*)d_in[5];
    const float* be1  = (const float*)d_in[6];
    const float* W2   = (const float*)d_in[7];
    const float* b2   = (const float*)d_in[8];
    const float* g2   = (const float*)d_in[9];
    const float* be2  = (const float*)d_in[10];
    const int*   ei   = (const int*)d_in[11];

    const int Nn = in_sizes[0] / HDIM;
    const int E  = in_sizes[1];
    const int* src = ei;
    const int* dst = ei + E;

    float* agg   = (float*)d_ws;
    float* stats = agg + (size_t)Nn * HDIM;
    float* S1a = stats,       *S2a = stats + 64;
    float* S1b = stats + 128, *S2b = stats + 192;
    float* sc1 = stats + 256, *sh1 = stats + 320;
    float* sc2 = stats + 384, *sh2 = stats + 448;
    float* z = (float*)d_out;   // z1, then overwritten in-place by z2, then BN+ReLU

    hipMemsetAsync(agg, 0, (size_t)Nn * HDIM * sizeof(float), stream);
    hipMemsetAsync(stats, 0, 512 * sizeof(float), stream);

    {
        int total = E * 16;
        scatter_k<<<(total + 255) / 256, 256, 0, stream>>>(
            (const float4*)x, ew, src, dst, agg, E);
    }

    const int gblocks = (Nn + 127) / 128;
    gemm_k<0><<<gblocks, 256, 0, stream>>>(x, agg, epsp, nullptr, nullptr,
                                           W1, b1, z, S1a, S2a, Nn);
    finalize_k<<<1, 64, 0, stream>>>(S1a, S2a, g1, be1, sc1, sh1, 1.0f / Nn);
    gemm_k<1><<<gblocks, 256, 0, stream>>>(z, nullptr, nullptr, sc1, sh1,
                                           W2, b2, z, S1b, S2b, Nn);
    finalize_k<<<1, 64, 0, stream>>>(S1b, S2b, g2, be2, sc2, sh2, 1.0f / Nn);

    {
        int total4 = Nn * 16;
        bnrelu_k<<<(total4 + 255) / 256, 256, 0, stream>>>(
            (float4*)z, sc2, sh2, total4);
    }
}

// Round 2
// 913.080 us; speedup vs baseline: 2.1961x; 2.1961x over previous
//
#include <hip/hip_runtime.h>

#define HDIM 64

// ================= counting-sort of edges by dst =================

__global__ __launch_bounds__(256) void hist_k(
    const int* __restrict__ dst, int* __restrict__ counts, int E)
{
    int e = blockIdx.x * 256 + threadIdx.x;
    if (e < E) atomicAdd(&counts[dst[e]], 1);
}

// block = 256 threads, 1024 elements/block. Exclusive scan -> offsets,
// per-block total -> blocksums[b].
__global__ __launch_bounds__(256) void scan1_k(
    const int* __restrict__ counts, int* __restrict__ offsets,
    int* __restrict__ blocksums, int Nn)
{
    __shared__ int sh[256];
    const int t = threadIdx.x;
    const int base = blockIdx.x * 1024 + t * 4;
    int v0 = (base + 0 < Nn) ? counts[base + 0] : 0;
    int v1 = (base + 1 < Nn) ? counts[base + 1] : 0;
    int v2 = (base + 2 < Nn) ? counts[base + 2] : 0;
    int v3 = (base + 3 < Nn) ? counts[base + 3] : 0;
    int tsum = v0 + v1 + v2 + v3;
    sh[t] = tsum;
    __syncthreads();
#pragma unroll
    for (int d = 1; d < 256; d <<= 1) {
        int y = (t >= d) ? sh[t - d] : 0;
        __syncthreads();
        sh[t] += y;
        __syncthreads();
    }
    int excl = sh[t] - tsum;
    if (t == 0) blocksums[blockIdx.x] = sh[255];
    if (base + 0 < Nn) offsets[base + 0] = excl;
    if (base + 1 < Nn) offsets[base + 1] = excl + v0;
    if (base + 2 < Nn) offsets[base + 2] = excl + v0 + v1;
    if (base + 3 < Nn) offsets[base + 3] = excl + v0 + v1 + v2;
}

__global__ __launch_bounds__(256) void scan2_k(int* __restrict__ blocksums, int NB)
{
    __shared__ int sh[256];
    const int t = threadIdx.x;
    int v = (t < NB) ? blocksums[t] : 0;
    sh[t] = v;
    __syncthreads();
#pragma unroll
    for (int d = 1; d < 256; d <<= 1) {
        int y = (t >= d) ? sh[t - d] : 0;
        __syncthreads();
        sh[t] += y;
        __syncthreads();
    }
    if (t < NB) blocksums[t] = sh[t] - v;   // exclusive
}

__global__ __launch_bounds__(256) void scan3_k(
    int* __restrict__ offsets, int* __restrict__ cursor,
    const int* __restrict__ blocksums, int Nn)
{
    const int t = threadIdx.x;
    const int base = blockIdx.x * 1024 + t * 4;
    const int add = blocksums[blockIdx.x];
#pragma unroll
    for (int i = 0; i < 4; ++i) {
        int idx = base + i;
        if (idx < Nn) {
            int o = offsets[idx] + add;
            offsets[idx] = o;
            cursor[idx] = o;
        }
    }
}

__global__ __launch_bounds__(256) void sort_k(
    const int* __restrict__ src, const int* __restrict__ dst,
    const float* __restrict__ ew, int* __restrict__ cursor,
    int2* __restrict__ edata, int E)
{
    int e = blockIdx.x * 256 + threadIdx.x;
    if (e >= E) return;
    int t = dst[e];
    int slot = atomicAdd(&cursor[t], 1);
    edata[slot] = make_int2(src[e], __float_as_int(ew[e]));
}

// ============== CSR aggregate + GIN update (no atomics) ==============
// 16 lanes per node; lane q owns float4 chunk q. h = (1+eps)*x + sum_e w*x[src]
__global__ __launch_bounds__(256) void agg_k(
    const float4* __restrict__ x4,
    const int* __restrict__ offsets, const int* __restrict__ cursor,
    const int2* __restrict__ edata, const float* __restrict__ epsp,
    float4* __restrict__ h4, int Nn)
{
    int idx = blockIdx.x * 256 + threadIdx.x;
    int node = idx >> 4;
    if (node >= Nn) return;
    int q = idx & 15;
    int start = offsets[node];
    int end = cursor[node];        // == offsets[node] + count[node]
    float4 acc = make_float4(0.f, 0.f, 0.f, 0.f);
    for (int e = start; e < end; ++e) {
        int2 p = edata[e];
        float w = __int_as_float(p.y);
        float4 xv = x4[(size_t)p.x * 16 + q];
        acc.x = fmaf(w, xv.x, acc.x);
        acc.y = fmaf(w, xv.y, acc.y);
        acc.z = fmaf(w, xv.z, acc.z);
        acc.w = fmaf(w, xv.w, acc.w);
    }
    float epsv = 1.0f + *epsp;
    float4 xs = x4[(size_t)node * 16 + q];
    acc.x = fmaf(epsv, xs.x, acc.x);
    acc.y = fmaf(epsv, xs.y, acc.y);
    acc.z = fmaf(epsv, xs.z, acc.z);
    acc.w = fmaf(epsv, xs.w, acc.w);
    h4[(size_t)node * 16 + q] = acc;
}

// ============ fused GEMM (+input transform) + BN-stats ============
// MODE 0: in = h (already GIN-updated)          -> z1 = h@W1 + b1, stats1
// MODE 1: in = z1, h = relu(z1*scale + shift)   -> z2 = h@W2 + b2, stats2
template <int MODE>
__global__ __launch_bounds__(256) void gemm_k(
    const float* __restrict__ in,
    const float* __restrict__ scale,
    const float* __restrict__ shift,
    const float* __restrict__ W,
    const float* __restrict__ bias,
    float* __restrict__ out,
    float* __restrict__ S1, float* __restrict__ S2,
    int Nn)
{
    __shared__ float Wl[64 * 64];
    __shared__ float hT[64 * 130];   // [k][row], rows padded 128->130

    const int t = threadIdx.x;
    const int base = blockIdx.x * 128;

    {
        const float4* W4 = (const float4*)W;
        float4* Wl4 = (float4*)Wl;
#pragma unroll
        for (int i = 0; i < 4; ++i) Wl4[t + i * 256] = W4[t + i * 256];
    }

    const float4* in4 = (const float4*)in;

#pragma unroll
    for (int i = 0; i < 8; ++i) {
        int c = t + i * 256;
        int row = c >> 4;
        int kc = c & 15;
        int k0 = kc * 4;
        float4 h4 = make_float4(0.f, 0.f, 0.f, 0.f);
        int grow = base + row;
        if (grow < Nn) {
            float4 v = in4[(size_t)grow * 16 + kc];
            if (MODE == 0) {
                h4 = v;
            } else {
                h4.x = fmaxf(fmaf(v.x, scale[k0 + 0], shift[k0 + 0]), 0.f);
                h4.y = fmaxf(fmaf(v.y, scale[k0 + 1], shift[k0 + 1]), 0.f);
                h4.z = fmaxf(fmaf(v.z, scale[k0 + 2], shift[k0 + 2]), 0.f);
                h4.w = fmaxf(fmaf(v.w, scale[k0 + 3], shift[k0 + 3]), 0.f);
            }
        }
        hT[(k0 + 0) * 130 + row] = h4.x;
        hT[(k0 + 1) * 130 + row] = h4.y;
        hT[(k0 + 2) * 130 + row] = h4.z;
        hT[(k0 + 3) * 130 + row] = h4.w;
    }
    __syncthreads();

    const int wv = t >> 6;
    const int lane = t & 63;
    const int c0 = wv * 16;
    const int r0 = lane * 2;

    float acc0[16], acc1[16];
#pragma unroll
    for (int j = 0; j < 16; ++j) { acc0[j] = 0.f; acc1[j] = 0.f; }

#pragma unroll 8
    for (int k = 0; k < 64; ++k) {
        float2 hv = *(const float2*)&hT[k * 130 + r0];
        const float4* wp = (const float4*)&Wl[k * 64 + c0];
        float wvv[16];
        *(float4*)&wvv[0]  = wp[0];
        *(float4*)&wvv[4]  = wp[1];
        *(float4*)&wvv[8]  = wp[2];
        *(float4*)&wvv[12] = wp[3];
#pragma unroll
        for (int j = 0; j < 16; ++j) {
            acc0[j] = fmaf(hv.x, wvv[j], acc0[j]);
            acc1[j] = fmaf(hv.y, wvv[j], acc1[j]);
        }
    }

    const int grow0 = base + r0;
    const int grow1 = grow0 + 1;
    const bool v0 = grow0 < Nn, v1 = grow1 < Nn;

    float zr0[16], zr1[16];
#pragma unroll
    for (int j = 0; j < 16; ++j) {
        float b = bias[c0 + j];
        zr0[j] = acc0[j] + b;
        zr1[j] = acc1[j] + b;
    }
    if (v0) {
        float4* o = (float4*)&out[(size_t)grow0 * 64 + c0];
        o[0] = make_float4(zr0[0], zr0[1], zr0[2], zr0[3]);
        o[1] = make_float4(zr0[4], zr0[5], zr0[6], zr0[7]);
        o[2] = make_float4(zr0[8], zr0[9], zr0[10], zr0[11]);
        o[3] = make_float4(zr0[12], zr0[13], zr0[14], zr0[15]);
    }
    if (v1) {
        float4* o = (float4*)&out[(size_t)grow1 * 64 + c0];
        o[0] = make_float4(zr1[0], zr1[1], zr1[2], zr1[3]);
        o[1] = make_float4(zr1[4], zr1[5], zr1[6], zr1[7]);
        o[2] = make_float4(zr1[8], zr1[9], zr1[10], zr1[11]);
        o[3] = make_float4(zr1[12], zr1[13], zr1[14], zr1[15]);
    }

    float s1[16], s2[16];
#pragma unroll
    for (int j = 0; j < 16; ++j) {
        float a = v0 ? zr0[j] : 0.f;
        float b = v1 ? zr1[j] : 0.f;
        s1[j] = a + b;
        s2[j] = a * a + b * b;
    }
#pragma unroll
    for (int m = 1; m < 64; m <<= 1) {
#pragma unroll
        for (int j = 0; j < 16; ++j) {
            s1[j] += __shfl_xor(s1[j], m);
            s2[j] += __shfl_xor(s2[j], m);
        }
    }
    if (lane == 0) {
#pragma unroll
        for (int j = 0; j < 16; ++j) {
            atomicAdd(&S1[c0 + j], s1[j]);
            atomicAdd(&S2[c0 + j], s2[j]);
        }
    }
}

__global__ __launch_bounds__(64) void finalize_k(
    const float* __restrict__ S1, const float* __restrict__ S2,
    const float* __restrict__ gamma, const float* __restrict__ beta,
    float* __restrict__ scale, float* __restrict__ shift, float invN)
{
    int c = threadIdx.x;
    float mean = S1[c] * invN;
    float var = fmaxf(S2[c] * invN - mean * mean, 0.f);
    float g = gamma[c] / sqrtf(var + 1e-5f);
    scale[c] = g;
    shift[c] = beta[c] - mean * g;
}

__global__ __launch_bounds__(256) void bnrelu_k(
    float4* __restrict__ z, const float* __restrict__ scale,
    const float* __restrict__ shift, int total4)
{
    int idx = blockIdx.x * 256 + threadIdx.x;
    if (idx >= total4) return;
    int c0 = (idx & 15) * 4;
    float4 v = z[idx];
    v.x = fmaxf(fmaf(v.x, scale[c0 + 0], shift[c0 + 0]), 0.f);
    v.y = fmaxf(fmaf(v.y, scale[c0 + 1], shift[c0 + 1]), 0.f);
    v.z = fmaxf(fmaf(v.z, scale[c0 + 2], shift[c0 + 2]), 0.f);
    v.w = fmaxf(fmaf(v.w, scale[c0 + 3], shift[c0 + 3]), 0.f);
    z[idx] = v;
}

extern "C" void kernel_launch(void* const* d_in, const int* in_sizes, int n_in,
                              void* d_out, int out_size, void* d_ws, size_t ws_size,
                              hipStream_t stream)
{
    const float* x    = (const float*)d_in[0];
    const float* ew   = (const float*)d_in[1];
    const float* epsp = (const float*)d_in[2];
    const float* W1   = (const float*)d_in[3];
    const float* b1   = (const float*)d_in[4];
    const float* g1   = (const float*)d_in[5];
    const float* be1  = (const float*)d_in[6];
    const float* W2   = (const float*)d_in[7];
    const float* b2   = (const float*)d_in[8];
    const float* g2   = (const float*)d_in[9];
    const float* be2  = (const float*)d_in[10];
    const int*   ei   = (const int*)d_in[11];

    const int Nn = in_sizes[0] / HDIM;
    const int E  = in_sizes[1];
    const int* src = ei;
    const int* dst = ei + E;

    // d_ws: h (GIN-updated features) + BN stats
    float* h     = (float*)d_ws;
    float* stats = h + (size_t)Nn * HDIM;
    float* S1a = stats,       *S2a = stats + 64;
    float* S1b = stats + 128, *S2b = stats + 192;
    float* sc1 = stats + 256, *sh1 = stats + 320;
    float* sc2 = stats + 384, *sh2 = stats + 448;

    // d_out doubles as sort scratch (dead before gemm<0> writes z1 there)
    char* ob = (char*)d_out;
    int2* edata    = (int2*)ob;                       // E * 8 B
    int*  counts   = (int*)(ob + (size_t)E * 8);      // Nn
    int*  offsets  = counts + Nn;                     // Nn
    int*  cursor   = offsets + Nn;                    // Nn
    int*  blocksums= cursor + Nn;                     // <=128
    float* z = (float*)d_out;

    const int NB = (Nn + 1023) / 1024;

    hipMemsetAsync(counts, 0, (size_t)Nn * sizeof(int), stream);
    hipMemsetAsync(stats, 0, 512 * sizeof(float), stream);

    hist_k<<<(E + 255) / 256, 256, 0, stream>>>(dst, counts, E);
    scan1_k<<<NB, 256, 0, stream>>>(counts, offsets, blocksums, Nn);
    scan2_k<<<1, 256, 0, stream>>>(blocksums, NB);
    scan3_k<<<NB, 256, 0, stream>>>(offsets, cursor, blocksums, Nn);
    sort_k<<<(E + 255) / 256, 256, 0, stream>>>(src, dst, ew, cursor, edata, E);

    agg_k<<<(Nn * 16 + 255) / 256, 256, 0, stream>>>(
        (const float4*)x, offsets, cursor, edata, epsp, (float4*)h, Nn);

    const int gblocks = (Nn + 127) / 128;
    gemm_k<0><<<gblocks, 256, 0, stream>>>(h, nullptr, nullptr,
                                           W1, b1, z, S1a, S2a, Nn);
    finalize_k<<<1, 64, 0, stream>>>(S1a, S2a, g1, be1, sc1, sh1, 1.0f / Nn);
    gemm_k<1><<<gblocks, 256, 0, stream>>>(z, sc1, sh1,
                                           W2, b2, z, S1b, S2b, Nn);
    finalize_k<<<1, 64, 0, stream>>>(S1b, S2b, g2, be2, sc2, sh2, 1.0f / Nn);

    {
        int total4 = Nn * 16;
        bnrelu_k<<<(total4 + 255) / 256, 256, 0, stream>>>(
            (float4*)z, sc2, sh2, total4);
    }
}

// Round 3
// 355.571 us; speedup vs baseline: 5.6395x; 2.5679x over previous
//
#include <hip/hip_runtime.h>

#define HDIM 64
#define NREP 64   // stats-accumulator replicas (kills same-address atomic contention)

// ================= counting-sort of edges by dst =================

__global__ __launch_bounds__(256) void hist_k(
    const int* __restrict__ dst, int* __restrict__ counts, int E)
{
    int e = blockIdx.x * 256 + threadIdx.x;
    if (e < E) atomicAdd(&counts[dst[e]], 1);
}

__global__ __launch_bounds__(256) void scan1_k(
    const int* __restrict__ counts, int* __restrict__ offsets,
    int* __restrict__ blocksums, int Nn)
{
    __shared__ int sh[256];
    const int t = threadIdx.x;
    const int base = blockIdx.x * 1024 + t * 4;
    int v0 = (base + 0 < Nn) ? counts[base + 0] : 0;
    int v1 = (base + 1 < Nn) ? counts[base + 1] : 0;
    int v2 = (base + 2 < Nn) ? counts[base + 2] : 0;
    int v3 = (base + 3 < Nn) ? counts[base + 3] : 0;
    int tsum = v0 + v1 + v2 + v3;
    sh[t] = tsum;
    __syncthreads();
#pragma unroll
    for (int d = 1; d < 256; d <<= 1) {
        int y = (t >= d) ? sh[t - d] : 0;
        __syncthreads();
        sh[t] += y;
        __syncthreads();
    }
    int excl = sh[t] - tsum;
    if (t == 0) blocksums[blockIdx.x] = sh[255];
    if (base + 0 < Nn) offsets[base + 0] = excl;
    if (base + 1 < Nn) offsets[base + 1] = excl + v0;
    if (base + 2 < Nn) offsets[base + 2] = excl + v0 + v1;
    if (base + 3 < Nn) offsets[base + 3] = excl + v0 + v1 + v2;
}

__global__ __launch_bounds__(256) void scan2_k(int* __restrict__ blocksums, int NB)
{
    __shared__ int sh[256];
    const int t = threadIdx.x;
    int v = (t < NB) ? blocksums[t] : 0;
    sh[t] = v;
    __syncthreads();
#pragma unroll
    for (int d = 1; d < 256; d <<= 1) {
        int y = (t >= d) ? sh[t - d] : 0;
        __syncthreads();
        sh[t] += y;
        __syncthreads();
    }
    if (t < NB) blocksums[t] = sh[t] - v;   // exclusive
}

__global__ __launch_bounds__(256) void scan3_k(
    int* __restrict__ offsets, int* __restrict__ cursor,
    const int* __restrict__ blocksums, int Nn)
{
    const int t = threadIdx.x;
    const int base = blockIdx.x * 1024 + t * 4;
    const int add = blocksums[blockIdx.x];
#pragma unroll
    for (int i = 0; i < 4; ++i) {
        int idx = base + i;
        if (idx < Nn) {
            int o = offsets[idx] + add;
            offsets[idx] = o;
            cursor[idx] = o;
        }
    }
}

__global__ __launch_bounds__(256) void sort_k(
    const int* __restrict__ src, const int* __restrict__ dst,
    const float* __restrict__ ew, int* __restrict__ cursor,
    int2* __restrict__ edata, int E)
{
    int e = blockIdx.x * 256 + threadIdx.x;
    if (e >= E) return;
    int t = dst[e];
    int slot = atomicAdd(&cursor[t], 1);
    edata[slot] = make_int2(src[e], __float_as_int(ew[e]));
}

// ============== CSR aggregate + GIN update (no atomics) ==============
__global__ __launch_bounds__(256) void agg_k(
    const float4* __restrict__ x4,
    const int* __restrict__ offsets, const int* __restrict__ cursor,
    const int2* __restrict__ edata, const float* __restrict__ epsp,
    float4* __restrict__ h4, int Nn)
{
    int idx = blockIdx.x * 256 + threadIdx.x;
    int node = idx >> 4;
    if (node >= Nn) return;
    int q = idx & 15;
    int start = offsets[node];
    int end = cursor[node];
    float4 acc = make_float4(0.f, 0.f, 0.f, 0.f);
    for (int e = start; e < end; ++e) {
        int2 p = edata[e];
        float w = __int_as_float(p.y);
        float4 xv = x4[(size_t)p.x * 16 + q];
        acc.x = fmaf(w, xv.x, acc.x);
        acc.y = fmaf(w, xv.y, acc.y);
        acc.z = fmaf(w, xv.z, acc.z);
        acc.w = fmaf(w, xv.w, acc.w);
    }
    float epsv = 1.0f + *epsp;
    float4 xs = x4[(size_t)node * 16 + q];
    acc.x = fmaf(epsv, xs.x, acc.x);
    acc.y = fmaf(epsv, xs.y, acc.y);
    acc.z = fmaf(epsv, xs.z, acc.z);
    acc.w = fmaf(epsv, xs.w, acc.w);
    h4[(size_t)node * 16 + q] = acc;
}

// ============ fused GEMM (+input transform) + BN-stats ============
// MODE 0: in = h                                -> z1 = h@W1 + b1, stats1
// MODE 1: in = z1, h = relu(z1*scale + shift)   -> z2 = h@W2 + b2, stats2
// stats go to replica (blockIdx & 63) -> no same-address atomic storm
template <int MODE>
__global__ __launch_bounds__(256) void gemm_k(
    const float* __restrict__ in,
    const float* __restrict__ scale,
    const float* __restrict__ shift,
    const float* __restrict__ W,
    const float* __restrict__ bias,
    float* __restrict__ out,
    float* __restrict__ S1, float* __restrict__ S2,
    int Nn)
{
    __shared__ float Wl[64 * 64];
    __shared__ float hT[64 * 130];

    const int t = threadIdx.x;
    const int base = blockIdx.x * 128;

    {
        const float4* W4 = (const float4*)W;
        float4* Wl4 = (float4*)Wl;
#pragma unroll
        for (int i = 0; i < 4; ++i) Wl4[t + i * 256] = W4[t + i * 256];
    }

    const float4* in4 = (const float4*)in;

#pragma unroll
    for (int i = 0; i < 8; ++i) {
        int c = t + i * 256;
        int row = c >> 4;
        int kc = c & 15;
        int k0 = kc * 4;
        float4 h4 = make_float4(0.f, 0.f, 0.f, 0.f);
        int grow = base + row;
        if (grow < Nn) {
            float4 v = in4[(size_t)grow * 16 + kc];
            if (MODE == 0) {
                h4 = v;
            } else {
                h4.x = fmaxf(fmaf(v.x, scale[k0 + 0], shift[k0 + 0]), 0.f);
                h4.y = fmaxf(fmaf(v.y, scale[k0 + 1], shift[k0 + 1]), 0.f);
                h4.z = fmaxf(fmaf(v.z, scale[k0 + 2], shift[k0 + 2]), 0.f);
                h4.w = fmaxf(fmaf(v.w, scale[k0 + 3], shift[k0 + 3]), 0.f);
            }
        }
        hT[(k0 + 0) * 130 + row] = h4.x;
        hT[(k0 + 1) * 130 + row] = h4.y;
        hT[(k0 + 2) * 130 + row] = h4.z;
        hT[(k0 + 3) * 130 + row] = h4.w;
    }
    __syncthreads();

    const int wv = t >> 6;
    const int lane = t & 63;
    const int c0 = wv * 16;
    const int r0 = lane * 2;

    float acc0[16], acc1[16];
#pragma unroll
    for (int j = 0; j < 16; ++j) { acc0[j] = 0.f; acc1[j] = 0.f; }

#pragma unroll 8
    for (int k = 0; k < 64; ++k) {
        float2 hv = *(const float2*)&hT[k * 130 + r0];
        const float4* wp = (const float4*)&Wl[k * 64 + c0];
        float wvv[16];
        *(float4*)&wvv[0]  = wp[0];
        *(float4*)&wvv[4]  = wp[1];
        *(float4*)&wvv[8]  = wp[2];
        *(float4*)&wvv[12] = wp[3];
#pragma unroll
        for (int j = 0; j < 16; ++j) {
            acc0[j] = fmaf(hv.x, wvv[j], acc0[j]);
            acc1[j] = fmaf(hv.y, wvv[j], acc1[j]);
        }
    }

    const int grow0 = base + r0;
    const int grow1 = grow0 + 1;
    const bool v0 = grow0 < Nn, v1 = grow1 < Nn;

    float zr0[16], zr1[16];
#pragma unroll
    for (int j = 0; j < 16; ++j) {
        float b = bias[c0 + j];
        zr0[j] = acc0[j] + b;
        zr1[j] = acc1[j] + b;
    }
    if (v0) {
        float4* o = (float4*)&out[(size_t)grow0 * 64 + c0];
        o[0] = make_float4(zr0[0], zr0[1], zr0[2], zr0[3]);
        o[1] = make_float4(zr0[4], zr0[5], zr0[6], zr0[7]);
        o[2] = make_float4(zr0[8], zr0[9], zr0[10], zr0[11]);
        o[3] = make_float4(zr0[12], zr0[13], zr0[14], zr0[15]);
    }
    if (v1) {
        float4* o = (float4*)&out[(size_t)grow1 * 64 + c0];
        o[0] = make_float4(zr1[0], zr1[1], zr1[2], zr1[3]);
        o[1] = make_float4(zr1[4], zr1[5], zr1[6], zr1[7]);
        o[2] = make_float4(zr1[8], zr1[9], zr1[10], zr1[11]);
        o[3] = make_float4(zr1[12], zr1[13], zr1[14], zr1[15]);
    }

    float s1[16], s2[16];
#pragma unroll
    for (int j = 0; j < 16; ++j) {
        float a = v0 ? zr0[j] : 0.f;
        float b = v1 ? zr1[j] : 0.f;
        s1[j] = a + b;
        s2[j] = a * a + b * b;
    }
#pragma unroll
    for (int m = 1; m < 64; m <<= 1) {
#pragma unroll
        for (int j = 0; j < 16; ++j) {
            s1[j] += __shfl_xor(s1[j], m);
            s2[j] += __shfl_xor(s2[j], m);
        }
    }
    if (lane == 0) {
        const int rep = blockIdx.x & (NREP - 1);
        float* S1r = S1 + rep * 64;
        float* S2r = S2 + rep * 64;
#pragma unroll
        for (int j = 0; j < 16; ++j) {
            atomicAdd(&S1r[c0 + j], s1[j]);
            atomicAdd(&S2r[c0 + j], s2[j]);
        }
    }
}

// ---------------- BN finalize: reduce replicas, form scale/shift ----------------
__global__ __launch_bounds__(64) void finalize_k(
    const float* __restrict__ S1, const float* __restrict__ S2,
    const float* __restrict__ gamma, const float* __restrict__ beta,
    float* __restrict__ scale, float* __restrict__ shift, float invN)
{
    int c = threadIdx.x;
    float s1 = 0.f, s2 = 0.f;
#pragma unroll 8
    for (int r = 0; r < NREP; ++r) {
        s1 += S1[r * 64 + c];
        s2 += S2[r * 64 + c];
    }
    float mean = s1 * invN;
    float var = fmaxf(s2 * invN - mean * mean, 0.f);
    float g = gamma[c] / sqrtf(var + 1e-5f);
    scale[c] = g;
    shift[c] = beta[c] - mean * g;
}

__global__ __launch_bounds__(256) void bnrelu_k(
    float4* __restrict__ z, const float* __restrict__ scale,
    const float* __restrict__ shift, int total4)
{
    int idx = blockIdx.x * 256 + threadIdx.x;
    if (idx >= total4) return;
    int c0 = (idx & 15) * 4;
    float4 v = z[idx];
    v.x = fmaxf(fmaf(v.x, scale[c0 + 0], shift[c0 + 0]), 0.f);
    v.y = fmaxf(fmaf(v.y, scale[c0 + 1], shift[c0 + 1]), 0.f);
    v.z = fmaxf(fmaf(v.z, scale[c0 + 2], shift[c0 + 2]), 0.f);
    v.w = fmaxf(fmaf(v.w, scale[c0 + 3], shift[c0 + 3]), 0.f);
    z[idx] = v;
}

extern "C" void kernel_launch(void* const* d_in, const int* in_sizes, int n_in,
                              void* d_out, int out_size, void* d_ws, size_t ws_size,
                              hipStream_t stream)
{
    const float* x    = (const float*)d_in[0];
    const float* ew   = (const float*)d_in[1];
    const float* epsp = (const float*)d_in[2];
    const float* W1   = (const float*)d_in[3];
    const float* b1   = (const float*)d_in[4];
    const float* g1   = (const float*)d_in[5];
    const float* be1  = (const float*)d_in[6];
    const float* W2   = (const float*)d_in[7];
    const float* b2   = (const float*)d_in[8];
    const float* g2   = (const float*)d_in[9];
    const float* be2  = (const float*)d_in[10];
    const int*   ei   = (const int*)d_in[11];

    const int Nn = in_sizes[0] / HDIM;
    const int E  = in_sizes[1];
    const int* src = ei;
    const int* dst = ei + E;

    // d_ws: h + replicated BN stats
    float* h     = (float*)d_ws;
    float* stats = h + (size_t)Nn * HDIM;
    float* S1a = stats;                    // NREP*64
    float* S2a = S1a + NREP * 64;
    float* S1b = S2a + NREP * 64;
    float* S2b = S1b + NREP * 64;
    float* sc1 = S2b + NREP * 64;
    float* sh1 = sc1 + 64;
    float* sc2 = sh1 + 64;
    float* sh2 = sc2 + 64;
    const size_t statsN = (size_t)NREP * 64 * 4 + 256;

    // d_out doubles as sort scratch (dead before gemm<0> writes z1 there)
    char* ob = (char*)d_out;
    int2* edata    = (int2*)ob;                       // E * 8 B
    int*  counts   = (int*)(ob + (size_t)E * 8);      // Nn
    int*  offsets  = counts + Nn;                     // Nn
    int*  cursor   = offsets + Nn;                    // Nn
    int*  blocksums= cursor + Nn;                     // <=128
    float* z = (float*)d_out;

    const int NB = (Nn + 1023) / 1024;

    hipMemsetAsync(counts, 0, (size_t)Nn * sizeof(int), stream);
    hipMemsetAsync(stats, 0, statsN * sizeof(float), stream);

    hist_k<<<(E + 255) / 256, 256, 0, stream>>>(dst, counts, E);
    scan1_k<<<NB, 256, 0, stream>>>(counts, offsets, blocksums, Nn);
    scan2_k<<<1, 256, 0, stream>>>(blocksums, NB);
    scan3_k<<<NB, 256, 0, stream>>>(offsets, cursor, blocksums, Nn);
    sort_k<<<(E + 255) / 256, 256, 0, stream>>>(src, dst, ew, cursor, edata, E);

    agg_k<<<(Nn * 16 + 255) / 256, 256, 0, stream>>>(
        (const float4*)x, offsets, cursor, edata, epsp, (float4*)h, Nn);

    const int gblocks = (Nn + 127) / 128;
    gemm_k<0><<<gblocks, 256, 0, stream>>>(h, nullptr, nullptr,
                                           W1, b1, z, S1a, S2a, Nn);
    finalize_k<<<1, 64, 0, stream>>>(S1a, S2a, g1, be1, sc1, sh1, 1.0f / Nn);
    gemm_k<1><<<gblocks, 256, 0, stream>>>(z, sc1, sh1,
                                           W2, b2, z, S1b, S2b, Nn);
    finalize_k<<<1, 64, 0, stream>>>(S1b, S2b, g2, be2, sc2, sh2, 1.0f / Nn);

    {
        int total4 = Nn * 16;
        bnrelu_k<<<(total4 + 255) / 256, 256, 0, stream>>>(
            (float4*)z, sc2, sh2, total4);
    }
}